// Round 2
// baseline (322.387 us; speedup 1.0000x reference)
//
#include <hip/hip_runtime.h>

// SNN membrane scan + spike + double-cumsum, chunk-pipelined producer/consumer.
//
// Pipeline over 8 chunks of 128 timesteps, one block (8 waves) per CU:
//   iter c: wave 0   scans chunk c   (global loads -> membrane recurrence -> spike
//                                     bitmasks into LDS; quad-buffered prefetch)
//           waves1-7 store chunk c-1 (replay LDS bitmasks with exact int math,
//                                     float4 stores: lane = 4 channels x 4 t-rows)
//   __syncthreads() per iter. Reads of chunk c overlap writes of chunk c-1.
//
// m recurrence order and fmaf identical to previous kernel -> bit-exact outputs.

#define T_LEN 1024
#define N_IN  512
#define BN    16384          // BATCH * N_IN
#define U     16             // timesteps per scan stage
#define CT    128            // timesteps per chunk
#define NC    (T_LEN / CT)   // 8 chunks

struct Buf { float c[U]; float v[U]; };

__device__ __forceinline__ void prefetch(Buf& b, const float* __restrict__ cp,
                                         const float* __restrict__ vp, int t0) {
    if (t0 >= T_LEN) return;
    const float* __restrict__ c = cp + (size_t)t0 * BN;
    const float* __restrict__ v = vp + (size_t)t0 * BN;
#pragma unroll
    for (int u = 0; u < U; ++u) {
        b.c[u] = c[(size_t)u * BN];
        b.v[u] = v[(size_t)u * BN];
    }
}

// Advance membrane 16 steps; bit u of result = spike at t0+u.
__device__ __forceinline__ unsigned process16(const Buf& b, float beta, float& m) {
    unsigned mask = 0u;
#pragma unroll
    for (int u = 0; u < U; ++u) {
        m = fmaf(beta, m, b.c[u]);              // exact same op/order as before
        mask |= (m >= b.v[u]) ? (1u << u) : 0u; // Heaviside(m - vth)
    }
    return mask;
}

__global__ __launch_bounds__(512, 2) void snn_scan(
        const float* __restrict__ cur, const float* __restrict__ beta,
        const float* __restrict__ vini, const float* __restrict__ vth,
        float* __restrict__ gz, float* __restrict__ zo, float* __restrict__ ml)
{
    __shared__ unsigned bits[T_LEN / 32][64];   // 8 KiB: [dword][channel-lane]

    const int lane   = threadIdx.x & 63;
    const int wave   = threadIdx.x >> 6;        // 0..7
    const int chbase = blockIdx.x * 64;         // first channel of this block

    // ---- wave-0 scan state (registers; dead in writer waves) ----------------
    float bta = 0.0f, m = 0.0f;
    const float* cp = nullptr;
    const float* vp = nullptr;
    Buf b0, b1, b2, b3;
    if (wave == 0) {
        const int i = chbase + lane;
        bta = beta[i & (N_IN - 1)];
        m   = vini[i];
        cp  = cur + i;
        vp  = vth + i;
        prefetch(b0, cp, vp, 0);
        prefetch(b1, cp, vp, U);
        prefetch(b2, cp, vp, 2 * U);
        prefetch(b3, cp, vp, 3 * U);
    }

    // ---- writer state: lane owns 4 consecutive channels, one t-row of 4 -----
    const int row_sub = lane >> 4;              // 0..3 : row within t-quad
    const int chgrp   = lane & 15;              // 0..15: 4-channel group
    const int wsel    = wave - 1;               // 0..6 : which quads this wave stores
    int C0 = 0, C1 = 0, C2 = 0, C3 = 0;         // c1 carries (exact int)
    int Z0 = 0, Z1 = 0, Z2 = 0, Z3 = 0;         // z  carries (exact int)
    float* __restrict__ gbase = gz + chbase + 4 * chgrp;
    float* __restrict__ zbase = zo + chbase + 4 * chgrp;

    for (int cc = 0; cc <= NC; ++cc) {
        if (wave == 0) {
            if (cc < NC) {
                const int t0 = cc * CT;
                unsigned ma, mb;
                ma = process16(b0, bta, m); prefetch(b0, cp, vp, t0 + 4 * U);
                mb = process16(b1, bta, m); prefetch(b1, cp, vp, t0 + 5 * U);
                bits[(t0 >> 5) + 0][lane] = ma | (mb << 16);
                ma = process16(b2, bta, m); prefetch(b2, cp, vp, t0 + 6 * U);
                mb = process16(b3, bta, m); prefetch(b3, cp, vp, t0 + 7 * U);
                bits[(t0 >> 5) + 1][lane] = ma | (mb << 16);
                ma = process16(b0, bta, m); prefetch(b0, cp, vp, t0 + 8 * U);
                mb = process16(b1, bta, m); prefetch(b1, cp, vp, t0 + 9 * U);
                bits[(t0 >> 5) + 2][lane] = ma | (mb << 16);
                ma = process16(b2, bta, m); prefetch(b2, cp, vp, t0 + 10 * U);
                mb = process16(b3, bta, m); prefetch(b3, cp, vp, t0 + 11 * U);
                bits[(t0 >> 5) + 3][lane] = ma | (mb << 16);
                if (cc == NC - 1) ml[chbase + lane] = m;   // m_last (B,N)
            }
        } else if (cc >= 1) {
            const int pc = cc - 1;                  // chunk being written out
            int qm = (pc * 32) % 7;                 // rotating quad-ownership tag
#pragma unroll
            for (int d = 0; d < 4; ++d) {           // 4 bit-dwords per chunk
                const uint4 u = *reinterpret_cast<const uint4*>(
                                    &bits[4 * pc + d][4 * chgrp]);
#pragma unroll
                for (int sub = 0; sub < 8; ++sub) { // 8 t-quads per dword
                    int zq0 = 0, zq1 = 0, zq2 = 0, zq3 = 0;
#pragma unroll
                    for (int r = 0; r < 4; ++r) {   // exact integer replay
                        const int bp = sub * 4 + r;
                        C0 += (int)((u.x >> bp) & 1u); Z0 += C0;
                        C1 += (int)((u.y >> bp) & 1u); Z1 += C1;
                        C2 += (int)((u.z >> bp) & 1u); Z2 += C2;
                        C3 += (int)((u.w >> bp) & 1u); Z3 += C3;
                        zq0 = (row_sub == r) ? Z0 : zq0;   // capture my row
                        zq1 = (row_sub == r) ? Z1 : zq1;
                        zq2 = (row_sub == r) ? Z2 : zq2;
                        zq3 = (row_sub == r) ? Z3 : zq3;
                    }
                    if (qm == wsel) {               // this wave stores this quad
                        const int q = pc * 32 + d * 8 + sub;       // global t-quad
                        const size_t roff = (size_t)(q * 4 + row_sub) * BN;
                        float4 zf = make_float4((float)zq0, (float)zq1,
                                                (float)zq2, (float)zq3);
                        float4 gf = make_float4(zq0 == 1 ? 1.0f : 0.0f,
                                                zq1 == 1 ? 1.0f : 0.0f,
                                                zq2 == 1 ? 1.0f : 0.0f,
                                                zq3 == 1 ? 1.0f : 0.0f);
                        *reinterpret_cast<float4*>(gbase + roff) = gf;
                        *reinterpret_cast<float4*>(zbase + roff) = zf;
                    }
                    qm = (qm == 6) ? 0 : qm + 1;
                }
            }
        }
        __syncthreads();
    }
}

extern "C" void kernel_launch(void* const* d_in, const int* in_sizes, int n_in,
                              void* d_out, int out_size, void* d_ws, size_t ws_size,
                              hipStream_t stream) {
    const float* cur  = (const float*)d_in[0];   // (T,B,N) fp32
    const float* beta = (const float*)d_in[1];   // (N,)
    const float* vini = (const float*)d_in[2];   // (B,N)
    const float* vth  = (const float*)d_in[3];   // (T,B,N)
    float* gz = (float*)d_out;                       // (T,B,N)
    float* zo = gz + (size_t)T_LEN * BN;             // (T,B,N)
    float* ml = zo + (size_t)T_LEN * BN;             // (B,N)
    snn_scan<<<BN / 64, 512, 0, stream>>>(cur, beta, vini, vth, gz, zo, ml);
}

// Round 4
// 252.859 us; speedup vs baseline: 1.2750x; 1.2750x over previous
//
#include <hip/hip_runtime.h>

// SNN membrane scan + spike + double-cumsum.
//
// Preferred path (needs 4 MB workspace):
//   Kernel 1 (snn_scan, 256 blk x 64 thr): exact sequential membrane recurrence,
//     pure-load quad-buffered pipeline (full vmcnt window for reads). Emits spike
//     bitmasks (1 bit/t, 2 MB) and packed (C,Z) carry snapshots every 32 t
//     (u32 = C | Z<<11, 2 MB). Both L2-resident for kernel 2.
//   Kernel 2 (snn_expand, 2048 blk x 256 thr): each wave owns 8 t-rows x 256
//     channels; replays <=31 exact integer steps from the carry snapshot, then
//     streams float4 stores (1 KB contiguous per wave-instruction).
// Fallback (ws too small): single-kernel two-phase version (R1, verified).
//
// All paths: identical fmaf order + exact integer cumsums -> bit-exact outputs.

#define T_LEN 1024
#define N_IN  512
#define BN    16384          // BATCH * N_IN
#define U     16             // timesteps per prefetch stage
#define DW    (T_LEN / 32)   // 32 bit-dwords per channel

struct Buf { float c[U]; float v[U]; };

__device__ __forceinline__ void prefetch(Buf& b, const float* __restrict__ cp,
                                         const float* __restrict__ vp, int t0) {
    if (t0 >= T_LEN) return;
    const float* __restrict__ c = cp + (size_t)t0 * BN;
    const float* __restrict__ v = vp + (size_t)t0 * BN;
#pragma unroll
    for (int u = 0; u < U; ++u) {
        b.c[u] = c[(size_t)u * BN];
        b.v[u] = v[(size_t)u * BN];
    }
}

// Advance membrane 16 steps; update exact integer carries; return spike mask.
__device__ __forceinline__ unsigned process16(const Buf& b, float beta, float& m,
                                              int& C, int& Z) {
    unsigned mask = 0u;
#pragma unroll
    for (int u = 0; u < U; ++u) {
        m = fmaf(beta, m, b.c[u]);              // exact same op/order as before
        const int s = (m >= b.v[u]) ? 1 : 0;    // Heaviside(m - vth)
        mask |= (unsigned)s << u;
        C += s;                                 // c1 cumsum (exact int)
        Z += C;                                 // z  double-cumsum (exact int)
    }
    return mask;
}

// ---------------------------- preferred path --------------------------------

__global__ __launch_bounds__(64, 1) void snn_scan(
        const float* __restrict__ cur, const float* __restrict__ beta,
        const float* __restrict__ vini, const float* __restrict__ vth,
        unsigned* __restrict__ bitsg, unsigned* __restrict__ Pc,
        float* __restrict__ ml)
{
    const int i = blockIdx.x * 64 + threadIdx.x;   // channel id (= b*N + n)
    const float bta = beta[i & (N_IN - 1)];
    float m = vini[i];
    int C = 0, Z = 0;

    const float* cp = cur + i;
    const float* vp = vth + i;

    Buf b0, b1, b2, b3;
    prefetch(b0, cp, vp, 0);
    prefetch(b1, cp, vp, U);
    prefetch(b2, cp, vp, 2 * U);
    prefetch(b3, cp, vp, 3 * U);

    for (int t0 = 0; t0 < T_LEN; t0 += 4 * U) {
        const int d = t0 >> 5;                       // dword index (t0 % 64 == 0)
        // carry state BEFORE t = 32*d  (C<=1024 -> 11 bits; Z<=524800 -> 21 bits)
        Pc[(size_t)d * BN + i] = (unsigned)C | ((unsigned)Z << 11);
        unsigned ma = process16(b0, bta, m, C, Z);   prefetch(b0, cp, vp, t0 + 4 * U);
        unsigned mb = process16(b1, bta, m, C, Z);   prefetch(b1, cp, vp, t0 + 5 * U);
        bitsg[(size_t)d * BN + i] = ma | (mb << 16);
        Pc[(size_t)(d + 1) * BN + i] = (unsigned)C | ((unsigned)Z << 11);
        ma = process16(b2, bta, m, C, Z);            prefetch(b2, cp, vp, t0 + 6 * U);
        mb = process16(b3, bta, m, C, Z);            prefetch(b3, cp, vp, t0 + 7 * U);
        bitsg[(size_t)(d + 1) * BN + i] = ma | (mb << 16);
    }
    ml[i] = m;   // m_last (B,N)
}

__global__ __launch_bounds__(256, 4) void snn_expand(
        const unsigned* __restrict__ bitsg, const unsigned* __restrict__ Pc,
        float* __restrict__ gz, float* __restrict__ zo)
{
    const int d  = blockIdx.x & (DW - 1);   // t-dword 0..31
    const int cb = blockIdx.x / DW;         // channel block 0..63
    const int cg = threadIdx.x & 63;        // 4-channel group within 256
    const int tt = threadIdx.x >> 6;        // wave id 0..3 -> owns 8 t-rows
    const int ch = cb * 256 + cg * 4;       // first of 4 consecutive channels

    const uint4 u  = *reinterpret_cast<const uint4*>(&bitsg[(size_t)d * BN + ch]);
    const uint4 p4 = *reinterpret_cast<const uint4*>(&Pc[(size_t)d * BN + ch]);
    int C0 = (int)(p4.x & 0x7FFu), Z0 = (int)(p4.x >> 11);
    int C1 = (int)(p4.y & 0x7FFu), Z1 = (int)(p4.y >> 11);
    int C2 = (int)(p4.z & 0x7FFu), Z2 = (int)(p4.z >> 11);
    int C3 = (int)(p4.w & 0x7FFu), Z3 = (int)(p4.w >> 11);

    // replay bits [0, 8*tt) -- wave-uniform trip count, exact integer math
    const int pre = tt * 8;
    for (int b = 0; b < pre; ++b) {
        C0 += (int)((u.x >> b) & 1u); Z0 += C0;
        C1 += (int)((u.y >> b) & 1u); Z1 += C1;
        C2 += (int)((u.z >> b) & 1u); Z2 += C2;
        C3 += (int)((u.w >> b) & 1u); Z3 += C3;
    }

    float* __restrict__ gp = gz + (size_t)(d * 32 + pre) * BN + ch;
    float* __restrict__ zp = zo + (size_t)(d * 32 + pre) * BN + ch;
#pragma unroll
    for (int r = 0; r < 8; ++r) {           // my 8 t-rows: t = 32d + pre + r
        const int b = pre + r;
        C0 += (int)((u.x >> b) & 1u); Z0 += C0;
        C1 += (int)((u.y >> b) & 1u); Z1 += C1;
        C2 += (int)((u.z >> b) & 1u); Z2 += C2;
        C3 += (int)((u.w >> b) & 1u); Z3 += C3;
        const float4 gf = make_float4(Z0 == 1 ? 1.0f : 0.0f,
                                      Z1 == 1 ? 1.0f : 0.0f,
                                      Z2 == 1 ? 1.0f : 0.0f,
                                      Z3 == 1 ? 1.0f : 0.0f);
        const float4 zf = make_float4((float)Z0, (float)Z1,
                                      (float)Z2, (float)Z3);
        *reinterpret_cast<float4*>(gp + (size_t)r * BN) = gf;   // Block.g fwd
        *reinterpret_cast<float4*>(zp + (size_t)r * BN) = zf;   // exact: z < 2^24
    }
}

// ---------------------------- fallback path ---------------------------------
// Single-kernel two-phase version (verified correct & 84 us in an earlier run).

__global__ __launch_bounds__(512, 2) void snn_fused(
        const float* __restrict__ cur, const float* __restrict__ beta,
        const float* __restrict__ vini, const float* __restrict__ vth,
        float* __restrict__ gz, float* __restrict__ zo, float* __restrict__ ml)
{
    __shared__ unsigned bits[T_LEN / 32][64];

    const int lane = threadIdx.x & 63;
    const int wave = threadIdx.x >> 6;
    const int i = blockIdx.x * 64 + lane;

    if (wave == 0) {
        const float bta = beta[i & (N_IN - 1)];
        float m = vini[i];
        int Cd = 0, Zd = 0;   // dummies for process16 signature
        const float* cp = cur + i;
        const float* vp = vth + i;

        Buf b0, b1, b2, b3;
        prefetch(b0, cp, vp, 0);
        prefetch(b1, cp, vp, U);
        prefetch(b2, cp, vp, 2 * U);
        prefetch(b3, cp, vp, 3 * U);

        for (int t0 = 0; t0 < T_LEN; t0 += 4 * U) {
            unsigned m0 = process16(b0, bta, m, Cd, Zd);
            prefetch(b0, cp, vp, t0 + 4 * U);
            unsigned m1 = process16(b1, bta, m, Cd, Zd);
            prefetch(b1, cp, vp, t0 + 5 * U);
            bits[t0 >> 5][lane] = m0 | (m1 << 16);
            unsigned m2 = process16(b2, bta, m, Cd, Zd);
            prefetch(b2, cp, vp, t0 + 6 * U);
            unsigned m3 = process16(b3, bta, m, Cd, Zd);
            prefetch(b3, cp, vp, t0 + 7 * U);
            bits[(t0 >> 5) + 1][lane] = m2 | (m3 << 16);
        }
        ml[i] = m;
    }
    __syncthreads();

    int C = 0, Z = 0;
    const int d0 = wave * 4;
    for (int d = 0; d < d0; ++d) {
        unsigned u = bits[d][lane];
#pragma unroll
        for (int b = 0; b < 32; ++b) { C += (u >> b) & 1u; Z += C; }
    }

    float* __restrict__ gp = gz + (size_t)(d0 * 32) * BN + i;
    float* __restrict__ zp = zo + (size_t)(d0 * 32) * BN + i;
    for (int d = 0; d < 4; ++d) {
        unsigned u = bits[d0 + d][lane];
#pragma unroll
        for (int b = 0; b < 32; ++b) {
            C += (u >> b) & 1u;
            Z += C;
            const size_t off = (size_t)(d * 32 + b) * BN;
            gp[off] = (Z == 1) ? 1.0f : 0.0f;
            zp[off] = (float)Z;
        }
    }
}

extern "C" void kernel_launch(void* const* d_in, const int* in_sizes, int n_in,
                              void* d_out, int out_size, void* d_ws, size_t ws_size,
                              hipStream_t stream) {
    const float* cur  = (const float*)d_in[0];   // (T,B,N) fp32
    const float* beta = (const float*)d_in[1];   // (N,)
    const float* vini = (const float*)d_in[2];   // (B,N)
    const float* vth  = (const float*)d_in[3];   // (T,B,N)
    float* gz = (float*)d_out;                       // (T,B,N)
    float* zo = gz + (size_t)T_LEN * BN;             // (T,B,N)
    float* ml = zo + (size_t)T_LEN * BN;             // (B,N)

    // workspace need: bits (2 MB) + packed carries (2 MB)
    const size_t need = (size_t)DW * BN * sizeof(unsigned) * 2;

    if (d_ws != nullptr && ws_size >= need) {
        unsigned* bitsg = (unsigned*)d_ws;
        unsigned* Pc = bitsg + (size_t)DW * BN;
        snn_scan<<<BN / 64, 64, 0, stream>>>(cur, beta, vini, vth, bitsg, Pc, ml);
        snn_expand<<<DW * (BN / 256), 256, 0, stream>>>(bitsg, Pc, gz, zo);
    } else {
        snn_fused<<<BN / 64, 512, 0, stream>>>(cur, beta, vini, vth, gz, zo, ml);
    }
}

// Round 5
// 244.357 us; speedup vs baseline: 1.3193x; 1.0348x over previous
//
#include <hip/hip_runtime.h>

// SNN membrane scan + spike + double-cumsum, two-kernel split.
//
// Kernel 1 (snn_scan, 256 blk x 192 thr = 3 waves):
//   wave 1 loads cur, wave 2 loads vth via global_load_lds (16B/lane) into a
//   double-buffered LDS ring (2 x 64-timestep segments, 64 KB total);
//   wave 0 runs the exact sequential membrane recurrence out of LDS and emits
//   spike bitmasks (1 bit/t) + packed (C,Z) carry snapshots every 32 t.
//   __syncthreads() per segment = publication barrier (implicit vmcnt(0) drain).
// Kernel 2 (snn_expand, 2048 blk x 256 thr): each wave owns 8 t-rows x 256
//   channels; replays <=31 exact integer steps from the carry snapshot, then
//   streams float4 stores (1 KB contiguous per wave-instruction).
// Fallback (ws too small): single-kernel two-phase version (verified).
//
// All paths: identical fmaf order + exact integer cumsums -> bit-exact outputs.

#define T_LEN 1024
#define N_IN  512
#define BN    16384          // BATCH * N_IN
#define U     16             // fallback: timesteps per prefetch stage
#define DW    (T_LEN / 32)   // 32 bit-dwords per channel
#define SEG_T 64             // timesteps per LDS segment
#define NSEG  (T_LEN / SEG_T)

// ---------------- global->LDS direct copy (16 B per lane, linear dest) ------
__device__ __forceinline__ void gload_lds16(const float* g, float* l) {
    __builtin_amdgcn_global_load_lds(
        (const __attribute__((address_space(1))) void*)g,
        (__attribute__((address_space(3))) void*)l, 16, 0, 0);
}

// Issue one 64-t segment of one array: 16 wave-instructions x 1 KB.
// Lane l covers t-row 4j + (l>>4), channels 4*(l&15)..+3.
// LDS layout: [t_row][ch] float, row stride 64 floats (256 B).
__device__ __forceinline__ void issue_seg(const float* __restrict__ src,
                                          float* dst, int s, size_t goff) {
#pragma unroll
    for (int j = 0; j < SEG_T / 4; ++j) {
        gload_lds16(src + (size_t)(SEG_T * s + 4 * j) * BN + goff, dst + j * 256);
    }
}

// ---------------------------- preferred path --------------------------------

__global__ __launch_bounds__(192, 1) void snn_scan(
        const float* __restrict__ cur, const float* __restrict__ beta,
        const float* __restrict__ vini, const float* __restrict__ vth,
        unsigned* __restrict__ bitsg, unsigned* __restrict__ Pc,
        float* __restrict__ ml)
{
    __shared__ float ldsC[2][SEG_T * 64];   // 2 x 16 KB
    __shared__ float ldsV[2][SEG_T * 64];   // 2 x 16 KB   (64 KB total)

    const int lane   = threadIdx.x & 63;
    const int wave   = threadIdx.x >> 6;    // 0 = scan, 1 = cur loader, 2 = vth
    const int chbase = blockIdx.x * 64;
    // per-lane global offset: (t-sub-row, 4-channel group)
    const size_t goff = (size_t)chbase + (size_t)(lane >> 4) * BN
                      + (size_t)(4 * (lane & 15));

    float bta = 0.0f, m = 0.0f;
    int C = 0, Z = 0;
    if (wave == 0) {
        bta = beta[(chbase + lane) & (N_IN - 1)];
        m   = vini[chbase + lane];
    }

    if (wave == 1) issue_seg(cur, &ldsC[0][0], 0, goff);
    if (wave == 2) issue_seg(vth, &ldsV[0][0], 0, goff);
    __syncthreads();                        // publishes segment 0

    for (int s = 0; s < NSEG; ++s) {
        const int cb = s & 1, nb = (s + 1) & 1;
        if (s + 1 < NSEG) {                 // prefetch next segment
            if (wave == 1) issue_seg(cur, &ldsC[nb][0], s + 1, goff);
            if (wave == 2) issue_seg(vth, &ldsV[nb][0], s + 1, goff);
        }
        if (wave == 0) {                    // consume current segment
            const float* lc = &ldsC[cb][lane];
            const float* lv = &ldsV[cb][lane];
            const int i = chbase + lane;
#pragma unroll
            for (int h = 0; h < SEG_T / 32; ++h) {
                const int d = s * (SEG_T / 32) + h;
                // carry state BEFORE t = 32*d (C<=1024: 11 bits; Z<=524800: 21)
                Pc[(size_t)d * BN + i] = (unsigned)C | ((unsigned)Z << 11);
                unsigned mask = 0u;
#pragma unroll
                for (int t = 0; t < 32; ++t) {
                    const float c = lc[(h * 32 + t) * 64];
                    const float v = lv[(h * 32 + t) * 64];
                    m = fmaf(bta, m, c);          // exact same op/order as before
                    const int sp = (m >= v) ? 1 : 0;
                    mask |= (unsigned)sp << t;
                    C += sp;                      // c1 cumsum (exact int)
                    Z += C;                       // z double-cumsum (exact int)
                }
                bitsg[(size_t)d * BN + i] = mask;
            }
        }
        __syncthreads();                    // publish s+1, release buf cb
    }
    if (wave == 0) ml[chbase + lane] = m;   // m_last (B,N)
}

__global__ __launch_bounds__(256, 4) void snn_expand(
        const unsigned* __restrict__ bitsg, const unsigned* __restrict__ Pc,
        float* __restrict__ gz, float* __restrict__ zo)
{
    const int d  = blockIdx.x & (DW - 1);   // t-dword 0..31
    const int cb = blockIdx.x / DW;         // channel block 0..63
    const int cg = threadIdx.x & 63;        // 4-channel group within 256
    const int tt = threadIdx.x >> 6;        // wave id 0..3 -> owns 8 t-rows
    const int ch = cb * 256 + cg * 4;       // first of 4 consecutive channels

    const uint4 u  = *reinterpret_cast<const uint4*>(&bitsg[(size_t)d * BN + ch]);
    const uint4 p4 = *reinterpret_cast<const uint4*>(&Pc[(size_t)d * BN + ch]);
    int C0 = (int)(p4.x & 0x7FFu), Z0 = (int)(p4.x >> 11);
    int C1 = (int)(p4.y & 0x7FFu), Z1 = (int)(p4.y >> 11);
    int C2 = (int)(p4.z & 0x7FFu), Z2 = (int)(p4.z >> 11);
    int C3 = (int)(p4.w & 0x7FFu), Z3 = (int)(p4.w >> 11);

    // replay bits [0, 8*tt) -- wave-uniform trip count, exact integer math
    const int pre = tt * 8;
    for (int b = 0; b < pre; ++b) {
        C0 += (int)((u.x >> b) & 1u); Z0 += C0;
        C1 += (int)((u.y >> b) & 1u); Z1 += C1;
        C2 += (int)((u.z >> b) & 1u); Z2 += C2;
        C3 += (int)((u.w >> b) & 1u); Z3 += C3;
    }

    float* __restrict__ gp = gz + (size_t)(d * 32 + pre) * BN + ch;
    float* __restrict__ zp = zo + (size_t)(d * 32 + pre) * BN + ch;
#pragma unroll
    for (int r = 0; r < 8; ++r) {           // my 8 t-rows: t = 32d + pre + r
        const int b = pre + r;
        C0 += (int)((u.x >> b) & 1u); Z0 += C0;
        C1 += (int)((u.y >> b) & 1u); Z1 += C1;
        C2 += (int)((u.z >> b) & 1u); Z2 += C2;
        C3 += (int)((u.w >> b) & 1u); Z3 += C3;
        const float4 gf = make_float4(Z0 == 1 ? 1.0f : 0.0f,
                                      Z1 == 1 ? 1.0f : 0.0f,
                                      Z2 == 1 ? 1.0f : 0.0f,
                                      Z3 == 1 ? 1.0f : 0.0f);
        const float4 zf = make_float4((float)Z0, (float)Z1,
                                      (float)Z2, (float)Z3);
        *reinterpret_cast<float4*>(gp + (size_t)r * BN) = gf;   // Block.g fwd
        *reinterpret_cast<float4*>(zp + (size_t)r * BN) = zf;   // exact: z < 2^24
    }
}

// ---------------------------- fallback path ---------------------------------
// Single-kernel two-phase version (verified correct in an earlier run).

struct Buf { float c[U]; float v[U]; };

__device__ __forceinline__ void prefetch(Buf& b, const float* __restrict__ cp,
                                         const float* __restrict__ vp, int t0) {
    if (t0 >= T_LEN) return;
    const float* __restrict__ c = cp + (size_t)t0 * BN;
    const float* __restrict__ v = vp + (size_t)t0 * BN;
#pragma unroll
    for (int u = 0; u < U; ++u) {
        b.c[u] = c[(size_t)u * BN];
        b.v[u] = v[(size_t)u * BN];
    }
}

__device__ __forceinline__ unsigned process16(const Buf& b, float beta, float& m) {
    unsigned mask = 0u;
#pragma unroll
    for (int u = 0; u < U; ++u) {
        m = fmaf(beta, m, b.c[u]);
        mask |= (m >= b.v[u]) ? (1u << u) : 0u;
    }
    return mask;
}

__global__ __launch_bounds__(512, 2) void snn_fused(
        const float* __restrict__ cur, const float* __restrict__ beta,
        const float* __restrict__ vini, const float* __restrict__ vth,
        float* __restrict__ gz, float* __restrict__ zo, float* __restrict__ ml)
{
    __shared__ unsigned bits[T_LEN / 32][64];

    const int lane = threadIdx.x & 63;
    const int wave = threadIdx.x >> 6;
    const int i = blockIdx.x * 64 + lane;

    if (wave == 0) {
        const float bta = beta[i & (N_IN - 1)];
        float m = vini[i];
        const float* cp = cur + i;
        const float* vp = vth + i;

        Buf b0, b1, b2, b3;
        prefetch(b0, cp, vp, 0);
        prefetch(b1, cp, vp, U);
        prefetch(b2, cp, vp, 2 * U);
        prefetch(b3, cp, vp, 3 * U);

        for (int t0 = 0; t0 < T_LEN; t0 += 4 * U) {
            unsigned m0 = process16(b0, bta, m);
            prefetch(b0, cp, vp, t0 + 4 * U);
            unsigned m1 = process16(b1, bta, m);
            prefetch(b1, cp, vp, t0 + 5 * U);
            bits[t0 >> 5][lane] = m0 | (m1 << 16);
            unsigned m2 = process16(b2, bta, m);
            prefetch(b2, cp, vp, t0 + 6 * U);
            unsigned m3 = process16(b3, bta, m);
            prefetch(b3, cp, vp, t0 + 7 * U);
            bits[(t0 >> 5) + 1][lane] = m2 | (m3 << 16);
        }
        ml[i] = m;
    }
    __syncthreads();

    int C = 0, Z = 0;
    const int d0 = wave * 4;
    for (int d = 0; d < d0; ++d) {
        unsigned u = bits[d][lane];
#pragma unroll
        for (int b = 0; b < 32; ++b) { C += (u >> b) & 1u; Z += C; }
    }

    float* __restrict__ gp = gz + (size_t)(d0 * 32) * BN + i;
    float* __restrict__ zp = zo + (size_t)(d0 * 32) * BN + i;
    for (int d = 0; d < 4; ++d) {
        unsigned u = bits[d0 + d][lane];
#pragma unroll
        for (int b = 0; b < 32; ++b) {
            C += (u >> b) & 1u;
            Z += C;
            const size_t off = (size_t)(d * 32 + b) * BN;
            gp[off] = (Z == 1) ? 1.0f : 0.0f;
            zp[off] = (float)Z;
        }
    }
}

extern "C" void kernel_launch(void* const* d_in, const int* in_sizes, int n_in,
                              void* d_out, int out_size, void* d_ws, size_t ws_size,
                              hipStream_t stream) {
    const float* cur  = (const float*)d_in[0];   // (T,B,N) fp32
    const float* beta = (const float*)d_in[1];   // (N,)
    const float* vini = (const float*)d_in[2];   // (B,N)
    const float* vth  = (const float*)d_in[3];   // (T,B,N)
    float* gz = (float*)d_out;                       // (T,B,N)
    float* zo = gz + (size_t)T_LEN * BN;             // (T,B,N)
    float* ml = zo + (size_t)T_LEN * BN;             // (B,N)

    // workspace need: bits (2 MB) + packed carries (2 MB)
    const size_t need = (size_t)DW * BN * sizeof(unsigned) * 2;

    if (d_ws != nullptr && ws_size >= need) {
        unsigned* bitsg = (unsigned*)d_ws;
        unsigned* Pc = bitsg + (size_t)DW * BN;
        snn_scan<<<BN / 64, 192, 0, stream>>>(cur, beta, vini, vth, bitsg, Pc, ml);
        snn_expand<<<DW * (BN / 256), 256, 0, stream>>>(bitsg, Pc, gz, zo);
    } else {
        snn_fused<<<BN / 64, 512, 0, stream>>>(cur, beta, vini, vth, gz, zo, ml);
    }
}